// Round 4
// baseline (1077.183 us; speedup 1.0000x reference)
//
#include <hip/hip_runtime.h>
#include <math.h>

#define BB 16
#define TT 16
#define KK 4
#define VV 10003
#define DD 256
#define CC 64
#define RPB 4           // rows per k_gemm block
#define VT  1280        // v-span per block: 1024 (4/thread packed) + 256 (1/thread)
#define NVT 8           // v-tiles; 8 tiles -> tile == bid%8 == XCD (stable)
#define VP 10016        // padded row stride for logits scratch
#define FNEG (-1e30f)

typedef float f32x4 __attribute__((ext_vector_type(4)));
// 4-float vector with only 4-byte alignment guaranteed (Wv row stride 10003
// floats is odd, so d-slices of a column group are not 16B-aligned)
typedef float f32x4u __attribute__((ext_vector_type(4), aligned(4)));

// ---------- top-4, branch-free named-scalar version (no runtime indexing,
// stays in VGPRs; list kept sorted desc under strict total order) ----------
struct L4 { float v0, v1, v2, v3; int i0, i1, i2, i3; };

__device__ __forceinline__ void l4_init(L4 &l) {
  l.v0 = l.v1 = l.v2 = l.v3 = FNEG;
  l.i0 = l.i1 = l.i2 = l.i3 = 0x7fffffff;
}
__device__ __forceinline__ bool better(float v, int ix, float v2, int ix2) {
  return (v > v2) || (v == v2 && ix < ix2);
}
__device__ __forceinline__ void l4_insert(L4 &l, float v, int ix) {
  const bool c0 = better(v, ix, l.v0, l.i0);
  const bool c1 = better(v, ix, l.v1, l.i1);
  const bool c2 = better(v, ix, l.v2, l.i2);
  const bool c3 = better(v, ix, l.v3, l.i3);
  // update back-to-front with OLD values (sorted => c0=>c1=>c2=>c3)
  l.v3 = c3 ? (c2 ? l.v2 : v) : l.v3;  l.i3 = c3 ? (c2 ? l.i2 : ix) : l.i3;
  l.v2 = c2 ? (c1 ? l.v1 : v) : l.v2;  l.i2 = c2 ? (c1 ? l.i1 : ix) : l.i2;
  l.v1 = c1 ? (c0 ? l.v0 : v) : l.v1;  l.i1 = c1 ? (c0 ? l.i0 : ix) : l.i1;
  l.v0 = c0 ? v : l.v0;                l.i0 = c0 ? ix : l.i0;
}
__device__ __forceinline__ void l4_merge(L4 &a, const L4 &b) {
  // top-4 of a union b; indices distinct, strict total order => unique result
  l4_insert(a, b.v0, b.i0);
  l4_insert(a, b.v1, b.i1);
  l4_insert(a, b.v2, b.i2);
  l4_insert(a, b.v3, b.i3);
}
__device__ __forceinline__ L4 l4_shfl_xor(const L4 &a, int off) {
  L4 o;
  o.v0 = __shfl_xor(a.v0, off); o.i0 = __shfl_xor(a.i0, off);
  o.v1 = __shfl_xor(a.v1, off); o.i1 = __shfl_xor(a.i1, off);
  o.v2 = __shfl_xor(a.v2, off); o.i2 = __shfl_xor(a.i2, off);
  o.v3 = __shfl_xor(a.v3, off); o.i3 = __shfl_xor(a.i3, off);
  return o;
}

// ---------- numpy pairwise_sum base case (8 <= n <= 128) — bit-exact ----------
__device__ float np_block_sum(const float* a, int n) {
  float r0=a[0],r1=a[1],r2=a[2],r3=a[3],r4=a[4],r5=a[5],r6=a[6],r7=a[7];
  int i;
  for (i = 8; i + 8 <= n; i += 8) {
    r0 += a[i+0]; r1 += a[i+1]; r2 += a[i+2]; r3 += a[i+3];
    r4 += a[i+4]; r5 += a[i+5]; r6 += a[i+6]; r7 += a[i+7];
  }
  float res = ((r0 + r1) + (r2 + r3)) + ((r4 + r5) + (r6 + r7));
  for (; i < n; ++i) res += a[i];
  return res;
}

// ---------- kernel 0: init chain + zero the k_red ticket counter ----------
__global__ void k_init(const int* __restrict__ loc_tar, int* __restrict__ chainA,
                       int* __restrict__ bar) {
  int t = threadIdx.x;            // 256 = B*T
  int b = t >> 4, j = t & 15;
  chainA[t] = (j == 0) ? loc_tar[b * TT] : 0;
  if (t == 0) bar[0] = 0;
}

// ---------- kernel 1: logits GEMM (UNCHANGED from passing round-3) ----------
__global__ __launch_bounds__(256, 1)
void k_gemm(const float* __restrict__ E, const float* __restrict__ zs,
            const float* __restrict__ Wv, const float* __restrict__ bv,
            const int* __restrict__ chain, float* __restrict__ Lg,
            int step, int N, int Mshift) {
  __shared__ __align__(16) float xs[RPB * DD];   // 4 KB (h rows, broadcast-read)
  __shared__ int cs[RPB];

  const int t = threadIdx.x;
  const int tile = blockIdx.x % NVT;          // tile == XCD (stable mapping)
  const int n0 = (blockIdx.x / NVT) * RPB;    // N is a multiple of RPB
  const int v0 = tile * VT;

  const int v4 = v0 + (t << 2);               // packed group; max 9983 < VV
  const int v1 = v0 + 1024 + t;               // extra column
  const int v1ok = (v1 < VV);
  const int v1c = v1ok ? v1 : (VV - 1);

  if (t < RPB) {
    int n = n0 + t;
    int c = chain[n * TT + step];
    if ((unsigned)c >= VV) c = 0;    // defensive
    cs[t] = c;
  }
  __syncthreads();

  // stage xs rows: h = E[c] + zs[b]  (single f32 add, np order)
  for (int e = t; e < RPB * DD; e += 256) {
    int r = e >> 8, d = e & 255;
    int n = n0 + r;
    int b = n >> Mshift;
    xs[e] = E[cs[r] * DD + d] + zs[b * DD + d];
  }
  __syncthreads();

  const float* w4p = Wv + v4;
  const float* w1p = Wv + v1c;

  float acc4[RPB][4];
  float acc1[RPB];
#pragma unroll
  for (int r = 0; r < RPB; ++r) {
    acc1[r] = 0.f;
#pragma unroll
    for (int j = 0; j < 4; ++j) acc4[r][j] = 0.f;
  }

  // 8-d groups, double-buffered (A/B): W from global, h from LDS
  f32x4u w4A[8], w4B[8];
  float  w1A[8], w1B[8];
  f32x4  h0A[RPB], h1A[RPB], h0B[RPB], h1B[RPB];

#pragma unroll
  for (int u = 0; u < 8; ++u) {
    w4A[u] = *(const f32x4u*)(w4p + (size_t)u * VV);
    w1A[u] = w1p[(size_t)u * VV];
  }
#pragma unroll
  for (int r = 0; r < RPB; ++r) {
    h0A[r] = *(const f32x4*)(xs + r * DD);
    h1A[r] = *(const f32x4*)(xs + r * DD + 4);
  }

  for (int d0 = 0; d0 < DD; d0 += 16) {
    const int dB = d0 + 8;
#pragma unroll
    for (int u = 0; u < 8; ++u) {
      w4B[u] = *(const f32x4u*)(w4p + (size_t)(dB + u) * VV);
      w1B[u] = w1p[(size_t)(dB + u) * VV];
    }
#pragma unroll
    for (int r = 0; r < RPB; ++r) {
      h0B[r] = *(const f32x4*)(xs + r * DD + dB);
      h1B[r] = *(const f32x4*)(xs + r * DD + dB + 4);
    }

#pragma unroll
    for (int u = 0; u < 8; ++u) {          // d ascending within group
#pragma unroll
      for (int r = 0; r < RPB; ++r) {
        const float hv = (u < 4) ? h0A[r][u] : h1A[r][u - 4];
#pragma unroll
        for (int j = 0; j < 4; ++j) acc4[r][j] = fmaf(hv, w4A[u][j], acc4[r][j]);
        acc1[r] = fmaf(hv, w1A[u], acc1[r]);
      }
    }

    const int dA = (d0 + 16 < DD) ? (d0 + 16) : 0;   // dummy reload last iter
#pragma unroll
    for (int u = 0; u < 8; ++u) {
      w4A[u] = *(const f32x4u*)(w4p + (size_t)(dA + u) * VV);
      w1A[u] = w1p[(size_t)(dA + u) * VV];
    }
#pragma unroll
    for (int r = 0; r < RPB; ++r) {
      h0A[r] = *(const f32x4*)(xs + r * DD + dA);
      h1A[r] = *(const f32x4*)(xs + r * DD + dA + 4);
    }

#pragma unroll
    for (int u = 0; u < 8; ++u) {
#pragma unroll
      for (int r = 0; r < RPB; ++r) {
        const float hv = (u < 4) ? h0B[r][u] : h1B[r][u - 4];
#pragma unroll
        for (int j = 0; j < 4; ++j) acc4[r][j] = fmaf(hv, w4B[u][j], acc4[r][j]);
        acc1[r] = fmaf(hv, w1B[u], acc1[r]);
      }
    }
  }

  // epilogue: bias after gemm (np), vectorized store for the packed group
  const f32x4u bv4 = *(const f32x4u*)(bv + v4);
#pragma unroll
  for (int r = 0; r < RPB; ++r) {
    f32x4 o;
#pragma unroll
    for (int j = 0; j < 4; ++j) o[j] = acc4[r][j] + bv4[j];
    *(f32x4*)(Lg + (size_t)(n0 + r) * VP + v4) = o;   // 16B aligned
  }
  if (v1ok) {
    const float bvv = bv[v1];
#pragma unroll
    for (int r = 0; r < RPB; ++r)
      Lg[(size_t)(n0 + r) * VP + v1] = acc1[r] + bvv;
  }
}

// ---------- kernel 2: fused np-exact max/top4/pairwise-lse + beam ----------
// Barrier-light rewrite of the passing k_red (3 barriers instead of ~25):
//  * segment-tree SETUP: each lane derives its leaf (base,n) arithmetically
//    by descending the split recurrence (no shared state, no barriers).
//  * val-tree DOWN-SWEEP: lane L computes node 63+L = leaf(2L)+leaf(2L+1),
//    then 6 shfl levels v(q) <- v(2q)+v(2q+1) — identical pairing and operand
//    order to val[p]=val[2p+1]+val[2p+2]: bit-exact.
//  * global max: every wave redundantly shfl-merges the 16 per-wave partials
//    (no extra barrier); wave 0 additionally merges the top4 lists.
// Then "last block does beam": release fence + ticket atomic; the block that
// draws ticket N-1 acquire-fences and runs the (unchanged) beam update.
__global__ __launch_bounds__(1024)
void k_red(const float* __restrict__ Lg, float* __restrict__ topP,
           int* __restrict__ topI, float* __restrict__ prob,
           const int* __restrict__ chain_cur, int* __restrict__ chain_next,
           int step, int* __restrict__ bar) {
  __shared__ __align__(16) float row[VV];   // exp'd values (pairwise sums)
  __shared__ float wmax[16];
  __shared__ float wv4[16 * 4];
  __shared__ int   wi4[16 * 4];
  __shared__ int   lastF;
  __shared__ int   sel_src[BB][8];
  __shared__ int   sel_tok[BB][8];

  const int n = blockIdx.x;
  const int t = threadIdx.x;
  const int lane = t & 63;
  const int wid = t >> 6;
  const float* grow = Lg + (size_t)n * VP;

  // ---- load: 3 x4 groups per thread (4t, 4096+4t, 8192+4t) ----
  const int va = t << 2;            // 0..4095, always valid
  const int vb = 4096 + (t << 2);   // 4096..8191, always valid
  const int vc = 8192 + (t << 2);   // valid fully for t<=451; partial t=452
  f32x4 xa = *(const f32x4*)(grow + va);
  f32x4 xb = *(const f32x4*)(grow + vb);
  f32x4 xc;
  const bool cfull = (vc + 3 < VV);
  if (cfull) {
    xc = *(const f32x4*)(grow + vc);
  } else {
#pragma unroll
    for (int j = 0; j < 4; ++j) xc[j] = (vc + j < VV) ? grow[vc + j] : FNEG;
  }

  // ---- scan: max + top4 (branch-free inserts, guarded for OOB) ----
  float m = FNEG;
  L4 top; l4_init(top);
#pragma unroll
  for (int j = 0; j < 4; ++j) { float x = xa[j]; if (x > m) m = x; l4_insert(top, x, va + j); }
#pragma unroll
  for (int j = 0; j < 4; ++j) { float x = xb[j]; if (x > m) m = x; l4_insert(top, x, vb + j); }
#pragma unroll
  for (int j = 0; j < 4; ++j) {
    if (vc + j < VV) { float x = xc[j]; if (x > m) m = x; l4_insert(top, x, vc + j); }
  }

  // intra-wave reduce (64 lanes, butterfly; distinct indices -> exact)
  for (int off = 32; off; off >>= 1) {
    float m2 = __shfl_xor(m, off);
    if (m2 > m) m = m2;
    L4 o = l4_shfl_xor(top, off);
    l4_merge(top, o);
  }
  if (lane == 0) {
    wmax[wid] = m;
    wv4[wid * 4 + 0] = top.v0; wi4[wid * 4 + 0] = top.i0;
    wv4[wid * 4 + 1] = top.v1; wi4[wid * 4 + 1] = top.i1;
    wv4[wid * 4 + 2] = top.v2; wi4[wid * 4 + 2] = top.i2;
    wv4[wid * 4 + 3] = top.v3; wi4[wid * 4 + 3] = top.i3;
  }
  __syncthreads();                                        // barrier #1

  // every wave redundantly merges the 16 partial maxima -> gm in all lanes
  float mm = wmax[lane & 15];
#pragma unroll
  for (int off = 8; off; off >>= 1) {
    float m2 = __shfl_xor(mm, off);
    if (m2 > mm) mm = m2;
  }
  const float gm = mm;

  // wave 0 additionally merges the 16 top4 partials (result in lane 0 = t 0)
  L4 aa; l4_init(aa);
  if (wid == 0) {
    const int g = lane & 15;
    aa.v0 = wv4[g * 4 + 0]; aa.i0 = wi4[g * 4 + 0];
    aa.v1 = wv4[g * 4 + 1]; aa.i1 = wi4[g * 4 + 1];
    aa.v2 = wv4[g * 4 + 2]; aa.i2 = wi4[g * 4 + 2];
    aa.v3 = wv4[g * 4 + 3]; aa.i3 = wi4[g * 4 + 3];
#pragma unroll
    for (int off = 8; off; off >>= 1) {
      L4 o = l4_shfl_xor(aa, off);
      l4_merge(aa, o);
    }
  }

  // exp pass: f32 sub, double exp, store f32 (identical values per v)
  {
    f32x4 ea, eb;
#pragma unroll
    for (int j = 0; j < 4; ++j) ea[j] = (float)exp((double)(xa[j] - gm));
#pragma unroll
    for (int j = 0; j < 4; ++j) eb[j] = (float)exp((double)(xb[j] - gm));
    *(f32x4*)(row + va) = ea;      // ds_write_b128, 16B aligned
    *(f32x4*)(row + vb) = eb;
    if (cfull) {
      f32x4 ec;
#pragma unroll
      for (int j = 0; j < 4; ++j) ec[j] = (float)exp((double)(xc[j] - gm));
      *(f32x4*)(row + vc) = ec;
    } else {
#pragma unroll
      for (int j = 0; j < 4; ++j)
        if (vc + j < VV) row[vc + j] = (float)exp((double)(xc[j] - gm));
    }
  }
  __syncthreads();                                        // barrier #2

  // ---- pairwise tree, single wave, no barriers ----
  float rootv = 0.f;
  if (t < 64) {
    // descend 6 levels to the level-6 node covering leaves 2t, 2t+1
    int base = 0, nn = VV;
#pragma unroll
    for (int k = 5; k >= 0; --k) {
      int half = nn >> 1;
      int n2 = half - (half & 7);
      if ((t >> k) & 1) { base += n2; nn -= n2; } else nn = n2;
    }
    int half = nn >> 1;
    int n2 = half - (half & 7);
    float sa = np_block_sum(&row[base], n2);          // leaf 2t   (left)
    float sb = np_block_sum(&row[base + n2], nn - n2); // leaf 2t+1 (right)
    float v = sa + sb;                                 // node 63+t
#pragma unroll
    for (int l = 0; l < 6; ++l) {                      // v(q) <- v(2q)+v(2q+1)
      float x0 = __shfl(v, t * 2);
      float x1 = __shfl(v, t * 2 + 1);
      v = x0 + x1;
    }
    rootv = v;                                         // lane 0: root sum
  }

  if (t == 0) {
    float ls = (float)log((double)rootv);
    topP[n * 4 + 0] = (aa.v0 - gm) - ls;  topI[n * 4 + 0] = aa.i0;
    topP[n * 4 + 1] = (aa.v1 - gm) - ls;  topI[n * 4 + 1] = aa.i1;
    topP[n * 4 + 2] = (aa.v2 - gm) - ls;  topI[n * 4 + 2] = aa.i2;
    topP[n * 4 + 3] = (aa.v3 - gm) - ls;  topI[n * 4 + 3] = aa.i3;
    __threadfence();                       // release: make topP/topI visible
    int ticket = atomicAdd(bar, 1);
    lastF = (ticket == (int)gridDim.x - 1);
  }
  __syncthreads();                                        // barrier #3
  if (!lastF) return;

  // ================= fused beam update (last block only) =================
  __threadfence();                         // acquire: see all rows' topP/topI
  if (t == 0) *bar = 0;                    // reset ticket for next dispatch

  if (step == 0) {
    for (int e = t; e < BB * KK * TT; e += 1024) {
      int dst = e >> 4, q = e & 15;
      int bb = dst >> 2, kk = dst & 3;
      int val;
      if (q == 1) {
        int tok = topI[bb * 4 + kk]; if ((unsigned)tok >= VV) tok = 0;
        val = tok;
      } else {
        val = chain_cur[bb * TT + q];
      }
      chain_next[dst * TT + q] = val;
    }
    if (t < BB * KK) {
      int bb = t >> 2, kk = t & 3;
      prob[bb * 8 + kk] = topP[bb * 4 + kk];
    }
    return;
  }

  const int M = (step == 1) ? 4 : 8;
  const int nc = M * 4;

  if (t < 512) {
    const int b = t >> 5;      // batch 0..15
    const int c = t & 31;      // candidate 0..31
    float act;
    if (c < nc) {
      int mi = c >> 2, k = c & 3;
      act = prob[b * 8 + mi] * topP[(b * M + mi) * 4 + k];
    } else {
      act = -INFINITY;
    }
    for (int j = 0; j < 8; ++j) {
      float rv = act; int ri = c;
#pragma unroll
      for (int off = 1; off < 32; off <<= 1) {
        float v2 = __shfl_xor(rv, off, 32);
        int   i2 = __shfl_xor(ri, off, 32);
        if (v2 > rv || (v2 == rv && i2 < ri)) { rv = v2; ri = i2; }
      }
      if (c == ri) act = -INFINITY;          // mark used
      if (c == 0) {
        int mi = ri >> 2, k = ri & 3;
        int src = b * M + mi;
        int tok = topI[src * 4 + k]; if ((unsigned)tok >= VV) tok = 0;
        sel_src[b][j] = src;
        sel_tok[b][j] = tok;
        prob[b * 8 + j] = rv;
      }
    }
  }
  __syncthreads();                                        // barrier #4 (last block)

  for (int e = t; e < BB * 8 * TT; e += 1024) {
    int dst = e >> 4, q = e & 15;
    int bb = dst >> 3, j = dst & 7;
    int src = sel_src[bb][j];
    int val = (q == step + 1) ? sel_tok[bb][j] : chain_cur[src * TT + q];
    chain_next[dst * TT + q] = val;
  }
}

// ---------- kernel 4: finalize: loc_chain + tim_chain (UNCHANGED) ----------
__global__ __launch_bounds__(64)
void k_final(const int* __restrict__ chain, const float* __restrict__ E,
             const float* __restrict__ Wc, const float* __restrict__ bc,
             const float* __restrict__ Wt, const float* __restrict__ zt,
             const float* __restrict__ Wzt, float* __restrict__ out) {
  int blk = blockIdx.x;           // 224 = B*(T-2)
  int b = blk / (TT - 2), t = blk % (TT - 2);
  int lane = threadIdx.x;         // 64 = C
  int loc = chain[(b * 8) * TT + 1 + t];   // best beam, positions 1..T-2
  if ((unsigned)loc >= VV) loc = 0;        // defensive
  double acc = (double)bc[lane];
  const float* er = E + loc * DD;
  for (int d = 0; d < DD; ++d) acc += (double)er[d] * (double)Wc[d * CC + lane];
  double val = tanh(acc) * (double)Wt[lane];
  const float* ztr = zt + b * DD;
#pragma unroll
  for (int q = 0; q < 4; ++q) val += (double)ztr[lane * 4 + q] * (double)Wzt[lane * 4 + q];
  for (int off = 32; off; off >>= 1) val += __shfl_down(val, off);
  if (lane == 0) {
    out[b * (TT - 2) + t] = (float)loc;                 // loc_chain as float
    out[BB * (TT - 2) + b * (TT - 2) + t] = (float)val; // tim_chain
  }
}

// ---------- host ----------
extern "C" void kernel_launch(void* const* d_in, const int* in_sizes, int n_in,
                              void* d_out, int out_size, void* d_ws, size_t ws_size,
                              hipStream_t stream) {
  const int*   loc_tar = (const int*)  d_in[0];
  const float* zs      = (const float*)d_in[1];
  const float* zt      = (const float*)d_in[2];
  const float* E       = (const float*)d_in[3];
  const float* Wv      = (const float*)d_in[4];
  const float* bv      = (const float*)d_in[5];
  const float* Wc      = (const float*)d_in[6];
  const float* bc      = (const float*)d_in[7];
  const float* Wt      = (const float*)d_in[8];
  const float* Wzt     = (const float*)d_in[9];
  float* out = (float*)d_out;

  char* w = (char*)d_ws;
  float* Lg     = (float*)(w);                   // 128*10016*4 = 5,128,192 B
  float* topP   = (float*)(w + 5128192);         // 512 f32 = 2048 B
  int*   topI   = (int*)  (w + 5130240);         // 512 int = 2048 B
  float* prob   = (float*)(w + 5132288);         // 128 f32 = 512 B
  int*   chainA = (int*)  (w + 5132800);         // 2048 int = 8192 B
  int*   chainB = (int*)  (w + 5140992);         // 2048 int = 8192 B
  int*   bar    = (int*)  (w + 5149184);         // ticket counter, 4 B

  k_init<<<1, 256, 0, stream>>>(loc_tar, chainA, bar);

  int N = BB;
  int* cur = chainA;
  int* nxt = chainB;
  for (int i = 0; i < TT - 1; ++i) {
    int Mshift = (i == 0) ? 0 : ((i == 1) ? 2 : 3);
    int nrg = N / RPB;
    k_gemm<<<nrg * NVT, 256, 0, stream>>>(E, zs, Wv, bv, cur, Lg, i, N, Mshift);
    k_red<<<N, 1024, 0, stream>>>(Lg, topP, topI, prob, cur, nxt, i, bar);
    int* t2 = cur; cur = nxt; nxt = t2;
    N = (i == 0) ? BB * KK : BB * 2 * KK;
  }

  k_final<<<BB * (TT - 2), 64, 0, stream>>>(cur, E, Wc, bc, Wt, zt, Wzt, out);
}

// Round 5
// 1013.952 us; speedup vs baseline: 1.0624x; 1.0624x over previous
//
#include <hip/hip_runtime.h>
#include <math.h>

#define BB 16
#define TT 16
#define KK 4
#define VV 10003
#define DD 256
#define CC 64
#define RPB 4           // rows per k_gemm block
#define VT  1280        // v-span per block: 1024 (4/thread packed) + 256 (1/thread)
#define NVT 8           // v-tiles; 8 tiles -> tile == bid%8 == XCD (stable)
#define VP 10016        // padded row stride for logits scratch
#define FNEG (-1e30f)

typedef float f32x4 __attribute__((ext_vector_type(4)));
// 4-float vector with only 4-byte alignment guaranteed (Wv row stride 10003
// floats is odd, so d-slices of a column group are not 16B-aligned)
typedef float f32x4u __attribute__((ext_vector_type(4), aligned(4)));

// ---------- top-4, branch-free named-scalar version (no runtime indexing,
// stays in VGPRs; list kept sorted desc under strict total order) ----------
struct L4 { float v0, v1, v2, v3; int i0, i1, i2, i3; };

__device__ __forceinline__ void l4_init(L4 &l) {
  l.v0 = l.v1 = l.v2 = l.v3 = FNEG;
  l.i0 = l.i1 = l.i2 = l.i3 = 0x7fffffff;
}
__device__ __forceinline__ bool better(float v, int ix, float v2, int ix2) {
  return (v > v2) || (v == v2 && ix < ix2);
}
__device__ __forceinline__ void l4_insert(L4 &l, float v, int ix) {
  const bool c0 = better(v, ix, l.v0, l.i0);
  const bool c1 = better(v, ix, l.v1, l.i1);
  const bool c2 = better(v, ix, l.v2, l.i2);
  const bool c3 = better(v, ix, l.v3, l.i3);
  // update back-to-front with OLD values (sorted => c0=>c1=>c2=>c3)
  l.v3 = c3 ? (c2 ? l.v2 : v) : l.v3;  l.i3 = c3 ? (c2 ? l.i2 : ix) : l.i3;
  l.v2 = c2 ? (c1 ? l.v1 : v) : l.v2;  l.i2 = c2 ? (c1 ? l.i1 : ix) : l.i2;
  l.v1 = c1 ? (c0 ? l.v0 : v) : l.v1;  l.i1 = c1 ? (c0 ? l.i0 : ix) : l.i1;
  l.v0 = c0 ? v : l.v0;                l.i0 = c0 ? ix : l.i0;
}
__device__ __forceinline__ void l4_merge(L4 &a, const L4 &b) {
  // top-4 of a union b; indices distinct, strict total order => unique result
  l4_insert(a, b.v0, b.i0);
  l4_insert(a, b.v1, b.i1);
  l4_insert(a, b.v2, b.i2);
  l4_insert(a, b.v3, b.i3);
}
__device__ __forceinline__ L4 l4_shfl_xor(const L4 &a, int off) {
  L4 o;
  o.v0 = __shfl_xor(a.v0, off); o.i0 = __shfl_xor(a.i0, off);
  o.v1 = __shfl_xor(a.v1, off); o.i1 = __shfl_xor(a.i1, off);
  o.v2 = __shfl_xor(a.v2, off); o.i2 = __shfl_xor(a.i2, off);
  o.v3 = __shfl_xor(a.v3, off); o.i3 = __shfl_xor(a.i3, off);
  return o;
}

// ---------- numpy pairwise_sum base case (8 <= n <= 128) — bit-exact ----------
__device__ float np_block_sum(const float* a, int n) {
  float r0=a[0],r1=a[1],r2=a[2],r3=a[3],r4=a[4],r5=a[5],r6=a[6],r7=a[7];
  int i;
  for (i = 8; i + 8 <= n; i += 8) {
    r0 += a[i+0]; r1 += a[i+1]; r2 += a[i+2]; r3 += a[i+3];
    r4 += a[i+4]; r5 += a[i+5]; r6 += a[i+6]; r7 += a[i+7];
  }
  float res = ((r0 + r1) + (r2 + r3)) + ((r4 + r5) + (r6 + r7));
  for (; i < n; ++i) res += a[i];
  return res;
}

// ---------- kernel 0: init chain ----------
__global__ void k_init(const int* __restrict__ loc_tar, int* __restrict__ chainA) {
  int t = threadIdx.x;            // 256 = B*T
  int b = t >> 4, j = t & 15;
  chainA[t] = (j == 0) ? loc_tar[b * TT] : 0;
}

// ---------- kernel 1: logits GEMM (UNCHANGED, proven) ----------
__global__ __launch_bounds__(256, 1)
void k_gemm(const float* __restrict__ E, const float* __restrict__ zs,
            const float* __restrict__ Wv, const float* __restrict__ bv,
            const int* __restrict__ chain, float* __restrict__ Lg,
            int step, int N, int Mshift) {
  __shared__ __align__(16) float xs[RPB * DD];   // 4 KB (h rows, broadcast-read)
  __shared__ int cs[RPB];

  const int t = threadIdx.x;
  const int tile = blockIdx.x % NVT;          // tile == XCD (stable mapping)
  const int n0 = (blockIdx.x / NVT) * RPB;    // N is a multiple of RPB
  const int v0 = tile * VT;

  const int v4 = v0 + (t << 2);               // packed group; max 9983 < VV
  const int v1 = v0 + 1024 + t;               // extra column
  const int v1ok = (v1 < VV);
  const int v1c = v1ok ? v1 : (VV - 1);

  if (t < RPB) {
    int n = n0 + t;
    int c = chain[n * TT + step];
    if ((unsigned)c >= VV) c = 0;    // defensive
    cs[t] = c;
  }
  __syncthreads();

  // stage xs rows: h = E[c] + zs[b]  (single f32 add, np order)
  for (int e = t; e < RPB * DD; e += 256) {
    int r = e >> 8, d = e & 255;
    int n = n0 + r;
    int b = n >> Mshift;
    xs[e] = E[cs[r] * DD + d] + zs[b * DD + d];
  }
  __syncthreads();

  const float* w4p = Wv + v4;
  const float* w1p = Wv + v1c;

  float acc4[RPB][4];
  float acc1[RPB];
#pragma unroll
  for (int r = 0; r < RPB; ++r) {
    acc1[r] = 0.f;
#pragma unroll
    for (int j = 0; j < 4; ++j) acc4[r][j] = 0.f;
  }

  // 8-d groups, double-buffered (A/B): W from global, h from LDS
  f32x4u w4A[8], w4B[8];
  float  w1A[8], w1B[8];
  f32x4  h0A[RPB], h1A[RPB], h0B[RPB], h1B[RPB];

#pragma unroll
  for (int u = 0; u < 8; ++u) {
    w4A[u] = *(const f32x4u*)(w4p + (size_t)u * VV);
    w1A[u] = w1p[(size_t)u * VV];
  }
#pragma unroll
  for (int r = 0; r < RPB; ++r) {
    h0A[r] = *(const f32x4*)(xs + r * DD);
    h1A[r] = *(const f32x4*)(xs + r * DD + 4);
  }

  for (int d0 = 0; d0 < DD; d0 += 16) {
    const int dB = d0 + 8;
#pragma unroll
    for (int u = 0; u < 8; ++u) {
      w4B[u] = *(const f32x4u*)(w4p + (size_t)(dB + u) * VV);
      w1B[u] = w1p[(size_t)(dB + u) * VV];
    }
#pragma unroll
    for (int r = 0; r < RPB; ++r) {
      h0B[r] = *(const f32x4*)(xs + r * DD + dB);
      h1B[r] = *(const f32x4*)(xs + r * DD + dB + 4);
    }

#pragma unroll
    for (int u = 0; u < 8; ++u) {          // d ascending within group
#pragma unroll
      for (int r = 0; r < RPB; ++r) {
        const float hv = (u < 4) ? h0A[r][u] : h1A[r][u - 4];
#pragma unroll
        for (int j = 0; j < 4; ++j) acc4[r][j] = fmaf(hv, w4A[u][j], acc4[r][j]);
        acc1[r] = fmaf(hv, w1A[u], acc1[r]);
      }
    }

    const int dA = (d0 + 16 < DD) ? (d0 + 16) : 0;   // dummy reload last iter
#pragma unroll
    for (int u = 0; u < 8; ++u) {
      w4A[u] = *(const f32x4u*)(w4p + (size_t)(dA + u) * VV);
      w1A[u] = w1p[(size_t)(dA + u) * VV];
    }
#pragma unroll
    for (int r = 0; r < RPB; ++r) {
      h0A[r] = *(const f32x4*)(xs + r * DD + dA);
      h1A[r] = *(const f32x4*)(xs + r * DD + dA + 4);
    }

#pragma unroll
    for (int u = 0; u < 8; ++u) {
#pragma unroll
      for (int r = 0; r < RPB; ++r) {
        const float hv = (u < 4) ? h0B[r][u] : h1B[r][u - 4];
#pragma unroll
        for (int j = 0; j < 4; ++j) acc4[r][j] = fmaf(hv, w4B[u][j], acc4[r][j]);
        acc1[r] = fmaf(hv, w1B[u], acc1[r]);
      }
    }
  }

  // epilogue: bias after gemm (np), vectorized store for the packed group
  const f32x4u bv4 = *(const f32x4u*)(bv + v4);
#pragma unroll
  for (int r = 0; r < RPB; ++r) {
    f32x4 o;
#pragma unroll
    for (int j = 0; j < 4; ++j) o[j] = acc4[r][j] + bv4[j];
    *(f32x4*)(Lg + (size_t)(n0 + r) * VP + v4) = o;   // 16B aligned
  }
  if (v1ok) {
    const float bvv = bv[v1];
#pragma unroll
    for (int r = 0; r < RPB; ++r)
      Lg[(size_t)(n0 + r) * VP + v1] = acc1[r] + bvv;
  }
}

// ---------- kernel 2: np-exact max/top4/pairwise-lse, 2 barriers ----------
// Barrier-light tree HW-verified bit-exact in round 4. Fused-beam/ticket
// REMOVED: __threadfence is a full device fence on gfx950 (buffer_wbl2 +
// buffer_inv per block -> L2 thrash; FETCH_SIZE tripled, +8us). Kernel
// boundaries give coherence for free.
__global__ __launch_bounds__(1024)
void k_red(const float* __restrict__ Lg, float* __restrict__ topP,
           int* __restrict__ topI) {
  __shared__ __align__(16) float row[VV];   // exp'd values (pairwise sums)
  __shared__ float wmax[16];
  __shared__ float wv4[16 * 4];
  __shared__ int   wi4[16 * 4];

  const int n = blockIdx.x;
  const int t = threadIdx.x;
  const int lane = t & 63;
  const int wid = t >> 6;
  const float* grow = Lg + (size_t)n * VP;

  // ---- load: 3 x4 groups per thread (4t, 4096+4t, 8192+4t) ----
  const int va = t << 2;            // 0..4095, always valid
  const int vb = 4096 + (t << 2);   // 4096..8191, always valid
  const int vc = 8192 + (t << 2);   // valid fully for t<=451; partial t=452
  f32x4 xa = *(const f32x4*)(grow + va);
  f32x4 xb = *(const f32x4*)(grow + vb);
  f32x4 xc;
  const bool cfull = (vc + 3 < VV);
  if (cfull) {
    xc = *(const f32x4*)(grow + vc);
  } else {
#pragma unroll
    for (int j = 0; j < 4; ++j) xc[j] = (vc + j < VV) ? grow[vc + j] : FNEG;
  }

  // ---- scan: max + top4 (branch-free inserts, guarded for OOB) ----
  float m = FNEG;
  L4 top; l4_init(top);
#pragma unroll
  for (int j = 0; j < 4; ++j) { float x = xa[j]; if (x > m) m = x; l4_insert(top, x, va + j); }
#pragma unroll
  for (int j = 0; j < 4; ++j) { float x = xb[j]; if (x > m) m = x; l4_insert(top, x, vb + j); }
#pragma unroll
  for (int j = 0; j < 4; ++j) {
    if (vc + j < VV) { float x = xc[j]; if (x > m) m = x; l4_insert(top, x, vc + j); }
  }

  // intra-wave reduce (64 lanes, butterfly; distinct indices -> exact)
  for (int off = 32; off; off >>= 1) {
    float m2 = __shfl_xor(m, off);
    if (m2 > m) m = m2;
    L4 o = l4_shfl_xor(top, off);
    l4_merge(top, o);
  }
  if (lane == 0) {
    wmax[wid] = m;
    wv4[wid * 4 + 0] = top.v0; wi4[wid * 4 + 0] = top.i0;
    wv4[wid * 4 + 1] = top.v1; wi4[wid * 4 + 1] = top.i1;
    wv4[wid * 4 + 2] = top.v2; wi4[wid * 4 + 2] = top.i2;
    wv4[wid * 4 + 3] = top.v3; wi4[wid * 4 + 3] = top.i3;
  }
  __syncthreads();                                        // barrier #1

  // every wave redundantly merges the 16 partial maxima -> gm in all lanes
  float mm = wmax[lane & 15];
#pragma unroll
  for (int off = 8; off; off >>= 1) {
    float m2 = __shfl_xor(mm, off);
    if (m2 > mm) mm = m2;
  }
  const float gm = mm;

  // wave 0 additionally merges the 16 top4 partials (result in lane 0 = t 0)
  L4 aa; l4_init(aa);
  if (wid == 0) {
    const int g = lane & 15;
    aa.v0 = wv4[g * 4 + 0]; aa.i0 = wi4[g * 4 + 0];
    aa.v1 = wv4[g * 4 + 1]; aa.i1 = wi4[g * 4 + 1];
    aa.v2 = wv4[g * 4 + 2]; aa.i2 = wi4[g * 4 + 2];
    aa.v3 = wv4[g * 4 + 3]; aa.i3 = wi4[g * 4 + 3];
#pragma unroll
    for (int off = 8; off; off >>= 1) {
      L4 o = l4_shfl_xor(aa, off);
      l4_merge(aa, o);
    }
  }

  // exp pass: f32 sub, double exp, store f32 (identical values per v)
  {
    f32x4 ea, eb;
#pragma unroll
    for (int j = 0; j < 4; ++j) ea[j] = (float)exp((double)(xa[j] - gm));
#pragma unroll
    for (int j = 0; j < 4; ++j) eb[j] = (float)exp((double)(xb[j] - gm));
    *(f32x4*)(row + va) = ea;      // ds_write_b128, 16B aligned
    *(f32x4*)(row + vb) = eb;
    if (cfull) {
      f32x4 ec;
#pragma unroll
      for (int j = 0; j < 4; ++j) ec[j] = (float)exp((double)(xc[j] - gm));
      *(f32x4*)(row + vc) = ec;
    } else {
#pragma unroll
      for (int j = 0; j < 4; ++j)
        if (vc + j < VV) row[vc + j] = (float)exp((double)(xc[j] - gm));
    }
  }
  __syncthreads();                                        // barrier #2

  // ---- pairwise tree, single wave, no barriers (HW-verified bit-exact) ----
  if (t < 64) {
    // descend 6 levels to the level-6 node covering leaves 2t, 2t+1
    int base = 0, nn = VV;
#pragma unroll
    for (int k = 5; k >= 0; --k) {
      int half = nn >> 1;
      int n2 = half - (half & 7);
      if ((t >> k) & 1) { base += n2; nn -= n2; } else nn = n2;
    }
    int half = nn >> 1;
    int n2 = half - (half & 7);
    float sa = np_block_sum(&row[base], n2);           // leaf 2t   (left)
    float sb = np_block_sum(&row[base + n2], nn - n2); // leaf 2t+1 (right)
    float v = sa + sb;                                 // node 63+t
#pragma unroll
    for (int l = 0; l < 6; ++l) {                      // v(q) <- v(2q)+v(2q+1)
      float x0 = __shfl(v, t * 2);
      float x1 = __shfl(v, t * 2 + 1);
      v = x0 + x1;
    }
    if (t == 0) {
      float ls = (float)log((double)v);
      topP[n * 4 + 0] = (aa.v0 - gm) - ls;  topI[n * 4 + 0] = aa.i0;
      topP[n * 4 + 1] = (aa.v1 - gm) - ls;  topI[n * 4 + 1] = aa.i1;
      topP[n * 4 + 2] = (aa.v2 - gm) - ls;  topI[n * 4 + 2] = aa.i2;
      topP[n * 4 + 3] = (aa.v3 - gm) - ls;  topI[n * 4 + 3] = aa.i3;
    }
  }
}

// ---------- kernel 3: beam update, wave-parallel (separate launch again) ----
__global__ __launch_bounds__(512)
void k_beam(const float* __restrict__ topP, const int* __restrict__ topI,
            float* __restrict__ prob, const int* __restrict__ chain_cur,
            int* __restrict__ chain_next, int step) {
  __shared__ int sel_src[BB][8];
  __shared__ int sel_tok[BB][8];

  const int tid = threadIdx.x;
  const int b = tid >> 5;      // batch 0..15
  const int c = tid & 31;      // candidate 0..31

  if (step == 0) {
    for (int e = tid; e < BB * KK * TT; e += 512) {
      int dst = e >> 4, q = e & 15;
      int bb = dst >> 2, kk = dst & 3;
      int val;
      if (q == 1) {
        int tok = topI[bb * 4 + kk]; if ((unsigned)tok >= VV) tok = 0;
        val = tok;
      } else {
        val = chain_cur[bb * TT + q];
      }
      chain_next[dst * TT + q] = val;
    }
    if (tid < BB * KK) {
      int bb = tid >> 2, kk = tid & 3;
      prob[bb * 8 + kk] = topP[bb * 4 + kk];
    }
    return;
  }

  const int M = (step == 1) ? 4 : 8;
  const int nc = M * 4;

  float act;
  if (c < nc) {
    int m = c >> 2, k = c & 3;
    act = prob[b * 8 + m] * topP[(b * M + m) * 4 + k];
  } else {
    act = -INFINITY;
  }

  for (int j = 0; j < 8; ++j) {
    float rv = act; int ri = c;
#pragma unroll
    for (int off = 1; off < 32; off <<= 1) {
      float v2 = __shfl_xor(rv, off, 32);
      int   i2 = __shfl_xor(ri, off, 32);
      if (v2 > rv || (v2 == rv && i2 < ri)) { rv = v2; ri = i2; }
    }
    if (c == ri) act = -INFINITY;          // mark used
    if (c == 0) {
      int m = ri >> 2, k = ri & 3;
      int src = b * M + m;
      int tok = topI[src * 4 + k]; if ((unsigned)tok >= VV) tok = 0;
      sel_src[b][j] = src;
      sel_tok[b][j] = tok;
      prob[b * 8 + j] = rv;
    }
  }
  __syncthreads();

  for (int e = tid; e < BB * 8 * TT; e += 512) {
    int dst = e >> 4, q = e & 15;
    int bb = dst >> 3, j = dst & 7;
    int src = sel_src[bb][j];
    int val = (q == step + 1) ? sel_tok[bb][j] : chain_cur[src * TT + q];
    chain_next[dst * TT + q] = val;
  }
}

// ---------- kernel 4: finalize: loc_chain + tim_chain (UNCHANGED) ----------
__global__ __launch_bounds__(64)
void k_final(const int* __restrict__ chain, const float* __restrict__ E,
             const float* __restrict__ Wc, const float* __restrict__ bc,
             const float* __restrict__ Wt, const float* __restrict__ zt,
             const float* __restrict__ Wzt, float* __restrict__ out) {
  int blk = blockIdx.x;           // 224 = B*(T-2)
  int b = blk / (TT - 2), t = blk % (TT - 2);
  int lane = threadIdx.x;         // 64 = C
  int loc = chain[(b * 8) * TT + 1 + t];   // best beam, positions 1..T-2
  if ((unsigned)loc >= VV) loc = 0;        // defensive
  double acc = (double)bc[lane];
  const float* er = E + loc * DD;
  for (int d = 0; d < DD; ++d) acc += (double)er[d] * (double)Wc[d * CC + lane];
  double val = tanh(acc) * (double)Wt[lane];
  const float* ztr = zt + b * DD;
#pragma unroll
  for (int q = 0; q < 4; ++q) val += (double)ztr[lane * 4 + q] * (double)Wzt[lane * 4 + q];
  for (int off = 32; off; off >>= 1) val += __shfl_down(val, off);
  if (lane == 0) {
    out[b * (TT - 2) + t] = (float)loc;                 // loc_chain as float
    out[BB * (TT - 2) + b * (TT - 2) + t] = (float)val; // tim_chain
  }
}

// ---------- host ----------
extern "C" void kernel_launch(void* const* d_in, const int* in_sizes, int n_in,
                              void* d_out, int out_size, void* d_ws, size_t ws_size,
                              hipStream_t stream) {
  const int*   loc_tar = (const int*)  d_in[0];
  const float* zs      = (const float*)d_in[1];
  const float* zt      = (const float*)d_in[2];
  const float* E       = (const float*)d_in[3];
  const float* Wv      = (const float*)d_in[4];
  const float* bv      = (const float*)d_in[5];
  const float* Wc      = (const float*)d_in[6];
  const float* bc      = (const float*)d_in[7];
  const float* Wt      = (const float*)d_in[8];
  const float* Wzt     = (const float*)d_in[9];
  float* out = (float*)d_out;

  char* w = (char*)d_ws;
  float* Lg     = (float*)(w);                   // 128*10016*4 = 5,128,192 B
  float* topP   = (float*)(w + 5128192);         // 512 f32 = 2048 B
  int*   topI   = (int*)  (w + 5130240);         // 512 int = 2048 B
  float* prob   = (float*)(w + 5132288);         // 128 f32 = 512 B
  int*   chainA = (int*)  (w + 5132800);         // 2048 int = 8192 B
  int*   chainB = (int*)  (w + 5140992);         // 2048 int = 8192 B

  k_init<<<1, 256, 0, stream>>>(loc_tar, chainA);

  int N = BB;
  int* cur = chainA;
  int* nxt = chainB;
  for (int i = 0; i < TT - 1; ++i) {
    int Mshift = (i == 0) ? 0 : ((i == 1) ? 2 : 3);
    int nrg = N / RPB;
    k_gemm<<<nrg * NVT, 256, 0, stream>>>(E, zs, Wv, bv, cur, Lg, i, N, Mshift);
    k_red<<<N, 1024, 0, stream>>>(Lg, topP, topI);
    k_beam<<<1, 512, 0, stream>>>(topP, topI, prob, cur, nxt, i);
    int* t2 = cur; cur = nxt; nxt = t2;
    N = (i == 0) ? BB * KK : BB * 2 * KK;
  }

  k_final<<<BB * (TT - 2), 64, 0, stream>>>(cur, E, Wc, bc, Wt, zt, Wzt, out);
}